// Round 7
// baseline (239.546 us; speedup 1.0000x reference)
//
#include <hip/hip_runtime.h>

#define IMG_W 1024
#define IMG_H 1024
#define BATCH 32
#define TALL  32                        // output rows per block (steady-state rolling)
#define TILES_PER_IMG (IMG_H / TALL)    // 32

typedef float vfloat4 __attribute__((ext_vector_type(4)));

__global__ __launch_bounds__(256) void conv3x3_kernel(
    const float* __restrict__ X,
    const float* __restrict__ wt,
    float* __restrict__ out)
{
    const int t    = blockIdx.x;                 // 0..1023
    const int b    = t / TILES_PER_IMG;          // batch
    const int y0   = (t % TILES_PER_IMG) * TALL; // first output row
    const int c0   = threadIdx.x * 4;            // first of 4 output cols
    const int lane = threadIdx.x & 63;

    const float* img = X + (size_t)b * IMG_H * IMG_W;

    const float w0 = wt[0], w1 = wt[1], w2 = wt[2];
    const float w3 = wt[3], w4 = wt[4], w5 = wt[5];
    const float w6 = wt[6], w7 = wt[7], w8 = wt[8];

    // V[slot]: raw loaded row (landing zone, 2-3 in flight at all times)
    // E[slot]: expanded 6-wide window (c0-1 .. c0+4), built once per row
    vfloat4 V[4];
    float   HL[4], HR[4];
    float   E[4][6];

    // issue the load for input row ry into slot s (no wait)
    auto issue = [&](int s, int ry) {
        float hl = 0.f, hr = 0.f;
        if (ry >= 0 && ry < IMG_H) {
            const float* p = img + (size_t)ry * IMG_W + c0;
            V[s] = *(const vfloat4*)p;
            if (lane == 0  && c0 > 0)         hl = p[-1];  // wave-boundary halo
            if (lane == 63 && c0 + 4 < IMG_W) hr = p[4];
        } else {
            V[s] = (vfloat4){0.f, 0.f, 0.f, 0.f};
        }
        HL[s] = hl; HR[s] = hr;
    };

    // consume V[s] -> E[s] (this is where the vmcnt wait lands)
    auto expand = [&](int s) {
        float left  = __shfl_up(V[s].w, 1);     // lane-1's col c0-1
        float right = __shfl_down(V[s].x, 1);   // lane+1's col c0+4
        left  = (lane == 0)  ? HL[s] : left;
        right = (lane == 63) ? HR[s] : right;
        E[s][0] = left;    E[s][1] = V[s].x; E[s][2] = V[s].y;
        E[s][3] = V[s].z;  E[s][4] = V[s].w; E[s][5] = right;
    };

    // prologue: rows y0-1 .. y0+2 in flight; expand the first two
#pragma unroll
    for (int j = 0; j < 4; ++j) issue(j, y0 - 1 + j);
    expand(0);   // row y0-1
    expand(1);   // row y0

    float* obase = out + ((size_t)b * IMG_H + y0) * IMG_W + c0;

    // steady state: each iteration { expand 1 row | 12 FMA | 1 NT store | issue 1 load }
    // load issued at iter i is consumed at iter i+2 -> constant ~2 loads in flight
#pragma unroll
    for (int i = 0; i < TALL; ++i) {
        expand((i + 2) & 3);                        // row y0+1+i (issued >=2 iters ago)
        const float (&ra)[6] = E[i & 3];            // row y0-1+i
        const float (&rb)[6] = E[(i + 1) & 3];      // row y0+i
        const float (&rc)[6] = E[(i + 2) & 3];      // row y0+1+i
        vfloat4 r;
#pragma unroll
        for (int j = 0; j < 4; ++j) {
            r[j] = w0 * ra[j] + w1 * ra[j + 1] + w2 * ra[j + 2]
                 + w3 * rb[j] + w4 * rb[j + 1] + w5 * rb[j + 2]
                 + w6 * rc[j] + w7 * rc[j + 1] + w8 * rc[j + 2];
        }
        __builtin_nontemporal_store(r, (vfloat4*)(obase + (size_t)i * IMG_W));

        if (i < TALL - 2) {
            issue(i & 3, y0 + 3 + i);               // reuse the slot just retired (ra)
            // pin: this load may not be sunk past this point (keeps prefetch
            // distance 2 real in the binary; unlike sched_barrier(0) it
            // constrains only this value, not the whole schedule)
            asm volatile("" : "+v"(V[i & 3]), "+v"(HL[i & 3]), "+v"(HR[i & 3]));
        }
    }
}

extern "C" void kernel_launch(void* const* d_in, const int* in_sizes, int n_in,
                              void* d_out, int out_size, void* d_ws, size_t ws_size,
                              hipStream_t stream) {
    const float* X  = (const float*)d_in[0];
    const float* wt = (const float*)d_in[1];
    float* out = (float*)d_out;

    dim3 grid(TILES_PER_IMG * BATCH);   // 1024 blocks = 4 per CU = 16 waves/CU
    dim3 block(256);                    // 256 threads * 4 cols = 1024 cols
    conv3x3_kernel<<<grid, block, 0, stream>>>(X, wt, out);
}